// Round 11
// baseline (288.345 us; speedup 1.0000x reference)
//
#include <hip/hip_runtime.h>

#define N_NODES 10000
#define CH 128
#define N_EDGES 320000
#define CAP 128   // bucket capacity; deg ~ Binomial(640k,1e-4): mean 64, sigma 8
#define CSTR 16   // cursor stride in ints = 64 B -> one counter per L2 line
                  // int +1 of each line is the untouched "base" (poison) value

#define NSLICE 8                                       // one slice per XCD
#define FILL_CHUNKS (N_EDGES / 256)                    // 1250 (exact)
#define FILL_BLOCKS (FILL_CHUNKS * NSLICE)             // 10000
#define CONV_THREADS (N_NODES * CH / 8)                // 160000 (8 floats/thread)
#define CONV_BLOCKS ((CONV_THREADS + 255) / 256)       // 625 (exact)
#define PACK_THREADS (128 * 128)                       // one thread per (o,k)
#define PACK_BLOCKS (PACK_THREADS / 256)               // 64
#define KSEG 5
#define WBK (KSEG * CH)                                // 640 = concat-K
#define NPB2 16                                        // nodes per fused block
#define AP 136                                         // LDS row pitch (ushorts): 272 B
                                                       // -> 16-lane col read = 2-way alias (free)

// ---------------------------------------------------------------------------
// Workspace layout (ws_size = 256 MiB; we use ~8.5 MB):
//   int    cursor[N_NODES*CSTR]            @ 0          (640,000 B, NOT memset)
//     counter = cursor[n*CSTR]; base = cursor[n*CSTR+1] (never written).
//     Harness poison is a uniform 4-byte pattern, so counter starts == base;
//     slot/deg are computed as (counter - base) -> poison-value-agnostic,
//     and the memset dispatch is deleted (3 graph nodes -> 2).
//   ushort adj   [N_NODES*CAP]             @ 640,000    (2.56 MB)
//   ushort xhi   [N_NODES*CH]  bf16(x)     @ 3,200,000  (2.56 MB)  L2-resident gather source
//   ushort xlo   [N_NODES*CH]  bf16(x-xhi) @ 5,760,000  (2.56 MB)
//   ushort wbt   [128][WBK]                @ 8,320,000  (160 KB)
//     row n: [Whi[n][:] | Wlo[n][:] | Bhi[n][:] | Blo[n][:] | Bhi[n][:]]
// GEMM: out = relu( [Ahi|Ahi|Xhi|Xhi|Xlo] @ wbt^T ), K=640:
//   = Ahi(Whi+Wlo) + Xhi(Bhi+Blo) + Xlo·Bhi ≈ agg·W + x·B
// agg hands off through LDS inside the fused kernel (no aggb buffer).
// ---------------------------------------------------------------------------

typedef __attribute__((ext_vector_type(8))) short short8v;   // 8 bf16 = 4 VGPR
typedef __attribute__((ext_vector_type(4))) float floatx4;   // MFMA C/D

__device__ __forceinline__ unsigned short f2bf(float f) {
    unsigned u = __float_as_uint(f);
    return (unsigned short)((u + 0x7FFFu + ((u >> 16) & 1u)) >> 16);  // RNE
}
__device__ __forceinline__ float bf2f(unsigned short h) {
    return __uint_as_float(((unsigned)h) << 16);
}

// Kernel 1: {x -> xhi,xlo split} || {XCD-sliced bucket fill} || {w,b pack}.
// Fill partition replicated NSLICE x: block (chunk,slice) scans 256 edges and
// handles only endpoints with node&7 == slice; blockIdx%8 round-robins XCDs,
// so each adj/cursor line is dirtied by exactly ONE XCD's L2 (kills the ~4x
// cross-XCD writeback amplification -- proven in round 6).
// Slot = atomicAdd(counter) - base, base = untouched poison int on the same
// line (loaded ~free with the atomic's line). No memset needed.
__global__ __launch_bounds__(256) void fill_conv_pack_kernel(const int* __restrict__ ei,
                                                             int* __restrict__ cursor,
                                                             unsigned short* __restrict__ adj,
                                                             const float* __restrict__ x,
                                                             unsigned short* __restrict__ xhi,
                                                             unsigned short* __restrict__ xlo,
                                                             const float* __restrict__ w,
                                                             const float* __restrict__ b,
                                                             unsigned short* __restrict__ wbt)
{
    const int bid = blockIdx.x;
    if (bid < CONV_BLOCKS) {
        // --- x -> (xhi, xlo): 8 elements/thread, fully coalesced ---
        const int t = bid * 256 + threadIdx.x;                   // < 160000 exact
        const float4 a = ((const float4*)x)[t * 2];
        const float4 c = ((const float4*)x)[t * 2 + 1];
        ushort4 h0, h1, l0, l1;
        h0.x = f2bf(a.x); l0.x = f2bf(a.x - bf2f(h0.x));
        h0.y = f2bf(a.y); l0.y = f2bf(a.y - bf2f(h0.y));
        h0.z = f2bf(a.z); l0.z = f2bf(a.z - bf2f(h0.z));
        h0.w = f2bf(a.w); l0.w = f2bf(a.w - bf2f(h0.w));
        h1.x = f2bf(c.x); l1.x = f2bf(c.x - bf2f(h1.x));
        h1.y = f2bf(c.y); l1.y = f2bf(c.y - bf2f(h1.y));
        h1.z = f2bf(c.z); l1.z = f2bf(c.z - bf2f(h1.z));
        h1.w = f2bf(c.w); l1.w = f2bf(c.w - bf2f(h1.w));
        ((ushort4*)xhi)[t * 2]     = h0;
        ((ushort4*)xhi)[t * 2 + 1] = h1;
        ((ushort4*)xlo)[t * 2]     = l0;
        ((ushort4*)xlo)[t * 2 + 1] = l1;
    } else if (bid < CONV_BLOCKS + FILL_BLOCKS) {
        // --- sliced bucket fill: 1 edge/thread, <=2 atomics, avg 0.25 ---
        const int fb    = bid - CONV_BLOCKS;
        const int slice = fb & (NSLICE - 1);
        const int chunk = fb >> 3;
        const int t = chunk * 256 + threadIdx.x;       // < 320000 exact
        const int2 p = ((const int2*)ei)[t];
        const int a = p.x, c = p.y;
        const bool aok = (unsigned)a < N_NODES && (unsigned)c < N_NODES;
        if (aok && (a & 7) == slice) {
            const unsigned base = (unsigned)cursor[a * CSTR + 1];   // same line, ~free
            const unsigned s0 = (unsigned)atomicAdd(&cursor[a * CSTR], 1) - base;
            if (s0 < CAP) adj[(size_t)a * CAP + s0] = (unsigned short)c;
        }
        if (aok && (c & 7) == slice) {
            const unsigned base = (unsigned)cursor[c * CSTR + 1];
            const unsigned s1 = (unsigned)atomicAdd(&cursor[c * CSTR], 1) - base;
            if (s1 < CAP) adj[(size_t)c * CAP + s1] = (unsigned short)a;
        }
    } else {
        // --- pack w,b into split-bf16 concat-K layout (16384 threads) ---
        const int t = (bid - CONV_BLOCKS - FILL_BLOCKS) * 256 + threadIdx.x;  // < 16384 exact
        const int n = t >> 7;          // output channel
        const int k = t & 127;         // input channel
        const float wv = w[n * CH + k];
        const float bv = b[n * CH + k];
        const unsigned short whi = f2bf(wv);
        const unsigned short wlo = f2bf(wv - bf2f(whi));
        const unsigned short bhi = f2bf(bv);
        const unsigned short blo = f2bf(bv - bf2f(bhi));
        unsigned short* row = wbt + (size_t)n * WBK;
        row[k]          = whi;
        row[CH + k]     = wlo;
        row[2 * CH + k] = bhi;
        row[3 * CH + k] = blo;
        row[4 * CH + k] = bhi;   // Bhi paired with Xlo segment
    }
}

// Kernel 2: FUSED gather-mean + MFMA GEMM + ReLU. 625 blocks x 512 threads
// (16 nodes/block = one 16-row m-tile). Round-7-proven bodies; deg computed
// as counter - base (poison-agnostic).
// Phase 1: 8 waves x 2 nodes, quarter-wave gather: lane = 16*h+l; quarter h
//   pulls neighbor 4*it+h; lane reads uint4 = 16 B = 8 bf16 ch. Agg row ->
//   LDS (AP-padded) -- no global aggb round-trip.
// Phase 2: wave wv owns output n-16th; K=640 concat MFMA loop (m89-verified
//   frag layouts, validated rounds 4-9); seg0/1 A-frags from LDS.
__global__ __launch_bounds__(512) void gather_mfma_kernel(const unsigned short* __restrict__ xhi,
                                                          const unsigned short* __restrict__ xlo,
                                                          const int* __restrict__ cursor,
                                                          const unsigned short* __restrict__ adj,
                                                          const unsigned short* __restrict__ wbt,
                                                          float* __restrict__ out)
{
    __shared__ unsigned short sh_a[NPB2 * AP];   // 4352 B, bf16 agg tile
    const int tid   = threadIdx.x;
    const int wv    = tid >> 6;                  // 0..7
    const int lane  = tid & 63;
    const int node0 = blockIdx.x * NPB2;         // grid = N_NODES/16 exactly

    // ---- Phase 1: gather + mean ----
    const int h = lane >> 4;                     // quarter 0..3 -> neighbor slot
    const int l = lane & 15;                     // 16 lanes x 8 ch = 128 ch

#pragma unroll
    for (int i = 0; i < 2; ++i) {
        const int nl   = wv * 2 + i;
        const int node = node0 + nl;
        const int2 cc  = *((const int2*)(cursor + node * CSTR));
        const int deg  = (int)((unsigned)cc.x - (unsigned)cc.y);   // counter - base
        const int d    = deg < CAP ? deg : CAP;
        const unsigned short* nb = adj + (size_t)node * CAP;

        float4 accA = {0.f, 0.f, 0.f, 0.f};
        float4 accB = {0.f, 0.f, 0.f, 0.f};
        const int nit = (d + 3) >> 2;
#pragma unroll 4
        for (int it = 0; it < nit; ++it) {
            const int idx = 4 * it + h;            // max 127 < CAP
            int j = nb[idx];
            j = j < N_NODES ? j : 0;               // clamp stale garbage (re-poison)
            const uint4 q = ((const uint4*)(xhi + (size_t)j * CH))[l];
            const float m = idx < d ? 1.0f : 0.0f; // branch-free tail mask
            accA.x += m * __uint_as_float(q.x << 16);
            accA.y += m * __uint_as_float(q.x & 0xffff0000u);
            accA.z += m * __uint_as_float(q.y << 16);
            accA.w += m * __uint_as_float(q.y & 0xffff0000u);
            accB.x += m * __uint_as_float(q.z << 16);
            accB.y += m * __uint_as_float(q.z & 0xffff0000u);
            accB.z += m * __uint_as_float(q.w << 16);
            accB.w += m * __uint_as_float(q.w & 0xffff0000u);
        }
        // reduce across quarters (lanes l, l+16, l+32, l+48)
        accA.x += __shfl_xor(accA.x, 16, 64);
        accA.y += __shfl_xor(accA.y, 16, 64);
        accA.z += __shfl_xor(accA.z, 16, 64);
        accA.w += __shfl_xor(accA.w, 16, 64);
        accB.x += __shfl_xor(accB.x, 16, 64);
        accB.y += __shfl_xor(accB.y, 16, 64);
        accB.z += __shfl_xor(accB.z, 16, 64);
        accB.w += __shfl_xor(accB.w, 16, 64);
        accA.x += __shfl_xor(accA.x, 32, 64);
        accA.y += __shfl_xor(accA.y, 32, 64);
        accA.z += __shfl_xor(accA.z, 32, 64);
        accA.w += __shfl_xor(accA.w, 32, 64);
        accB.x += __shfl_xor(accB.x, 32, 64);
        accB.y += __shfl_xor(accB.y, 32, 64);
        accB.z += __shfl_xor(accB.z, 32, 64);
        accB.w += __shfl_xor(accB.w, 32, 64);

        if (h == 0) {
            const float inv = deg > 0 ? 1.0f / (float)deg : 0.0f;
            uint4 o;
            o.x = (unsigned)f2bf(accA.x * inv) | ((unsigned)f2bf(accA.y * inv) << 16);
            o.y = (unsigned)f2bf(accA.z * inv) | ((unsigned)f2bf(accA.w * inv) << 16);
            o.z = (unsigned)f2bf(accB.x * inv) | ((unsigned)f2bf(accB.y * inv) << 16);
            o.w = (unsigned)f2bf(accB.z * inv) | ((unsigned)f2bf(accB.w * inv) << 16);
            ((uint4*)(sh_a + (size_t)nl * AP))[l] = o;   // ch 8l..8l+7, 2-way alias
        }
    }
    __syncthreads();

    // ---- Phase 2: out = relu(Mcat @ wbt^T) for this block's 16 rows ----
    const int r  = lane & 15;
    const int q  = lane >> 4;
    const int n0 = wv * 16;                      // output-channel 16th
    const unsigned short* brow = wbt + (size_t)(n0 + r) * WBK;
    floatx4 acc = {0.f, 0.f, 0.f, 0.f};

#pragma unroll
    for (int seg = 0; seg < KSEG; ++seg) {
        const int wk = seg * CH;
#pragma unroll
        for (int ks = 0; ks < 4; ++ks) {
            const int k0 = ks * 32 + q * 8;
            short8v af;
            if (seg < 2) {
                af = *(const short8v*)(sh_a + (size_t)r * AP + k0);              // LDS
            } else if (seg < 4) {
                af = *(const short8v*)(xhi + (size_t)(node0 + r) * CH + k0);     // L2-hot
            } else {
                af = *(const short8v*)(xlo + (size_t)(node0 + r) * CH + k0);     // L2-hot
            }
            const short8v bf = *(const short8v*)(brow + wk + k0);
            acc = __builtin_amdgcn_mfma_f32_16x16x32_bf16(af, bf, acc, 0, 0, 0);
        }
    }

    const int mbase = node0 + q * 4;
#pragma unroll
    for (int rr = 0; rr < 4; ++rr) {
        float v = acc[rr];
        v = v > 0.f ? v : 0.f;
        out[(size_t)(mbase + rr) * CH + n0 + r] = v;
    }
}

// ---------------------------------------------------------------------------
extern "C" void kernel_launch(void* const* d_in, const int* in_sizes, int n_in,
                              void* d_out, int out_size, void* d_ws, size_t ws_size,
                              hipStream_t stream)
{
    const float* x  = (const float*)d_in[0];
    const int*   ei = (const int*)d_in[1];   // (E,2) int32
    const float* w  = (const float*)d_in[2];
    const float* b  = (const float*)d_in[3];
    float*       out = (float*)d_out;

    int*            cursor = (int*)d_ws;                                    // @ 0
    unsigned short* adj    = (unsigned short*)((char*)d_ws + 640000);       // 2.56 MB
    unsigned short* xhi    = (unsigned short*)((char*)d_ws + 3200000);      // 2.56 MB
    unsigned short* xlo    = (unsigned short*)((char*)d_ws + 5760000);      // 2.56 MB
    unsigned short* wbt    = (unsigned short*)((char*)d_ws + 8320000);      // 160 KB

    // no memset: cursor baseline is read from the untouched poison int on
    // each counter's cache line (poison-value-agnostic counting).

    fill_conv_pack_kernel<<<CONV_BLOCKS + FILL_BLOCKS + PACK_BLOCKS, 256, 0, stream>>>(
        ei, cursor, adj, x, xhi, xlo, w, b, wbt);
    gather_mfma_kernel<<<N_NODES / NPB2, 512, 0, stream>>>(xhi, xlo, cursor, adj, wbt, out);
}

// Round 12
// 125.705 us; speedup vs baseline: 2.2938x; 2.2938x over previous
//
#include <hip/hip_runtime.h>

#define N_NODES 10000
#define CH 128
#define N_EDGES 320000
#define CAP 128   // bucket capacity; deg ~ Binomial(640k,1e-4): mean 64, sigma 8
#define CSTR 16   // cursor stride in ints = 64 B -> one counter per L2 line

#define NSLICE 8                                       // one slice per XCD
#define FILL_CHUNKS (N_EDGES / 256)                    // 1250 (exact)
#define FILL_BLOCKS (FILL_CHUNKS * NSLICE)             // 10000
#define CONV_THREADS (N_NODES * CH / 8)                // 160000 (8 floats/thread)
#define CONV_BLOCKS ((CONV_THREADS + 255) / 256)       // 625 (exact)
#define PACK_THREADS (128 * 128)                       // one thread per (o,k)
#define PACK_BLOCKS (PACK_THREADS / 256)               // 64
#define KSEG 5
#define WBK (KSEG * CH)                                // 640 = concat-K
#define NPB2 16                                        // nodes per fused block
#define AP 136                                         // LDS row pitch (ushorts): 272 B
                                                       // -> 16-lane col read = 2-way alias (free)

// ---------------------------------------------------------------------------
// Workspace layout (ws_size = 256 MiB; we use ~8.5 MB):
//   int    cursor[N_NODES*CSTR]            @ 0          (640,000 B, memset 0)
//     NOTE (r11 lesson): cursor lines must be touched ONLY by atomics during
//     fill -- mixing plain loads on the same line collapses the L2 atomic
//     fast-path (measured 5x kernel regression, 47 MB refetch).
//   ushort adj   [N_NODES*CAP]             @ 640,000    (2.56 MB)
//   ushort xhi   [N_NODES*CH]  bf16(x)     @ 3,200,000  (2.56 MB)  L2-resident gather source
//   ushort xlo   [N_NODES*CH]  bf16(x-xhi) @ 5,760,000  (2.56 MB)
//   ushort wbt   [128][WBK]                @ 8,320,000  (160 KB)
//     row n: [Whi[n][:] | Wlo[n][:] | Bhi[n][:] | Blo[n][:] | Bhi[n][:]]
// GEMM: out = relu( [Ahi|Ahi|Xhi|Xhi|Xlo] @ wbt^T ), K=640:
//   = Ahi(Whi+Wlo) + Xhi(Bhi+Blo) + Xlo·Bhi ≈ agg·W + x·B
// agg hands off through LDS inside the fused kernel (no aggb buffer).
// ---------------------------------------------------------------------------

typedef __attribute__((ext_vector_type(8))) short short8v;   // 8 bf16 = 4 VGPR
typedef __attribute__((ext_vector_type(4))) float floatx4;   // MFMA C/D

__device__ __forceinline__ unsigned short f2bf(float f) {
    unsigned u = __float_as_uint(f);
    return (unsigned short)((u + 0x7FFFu + ((u >> 16) & 1u)) >> 16);  // RNE
}
__device__ __forceinline__ float bf2f(unsigned short h) {
    return __uint_as_float(((unsigned)h) << 16);
}

// Kernel 1: {x -> xhi,xlo split} || {XCD-sliced bucket fill} || {w,b pack}.
// Exact round-7 body (best measured config, 124.9 us).
// Fill partition replicated NSLICE x: block (chunk,slice) scans 256 edges and
// handles only endpoints with node&7 == slice; blockIdx%8 round-robins XCDs,
// so each adj/cursor line is dirtied by exactly ONE XCD's L2 (kills the ~4x
// cross-XCD writeback amplification -- proven in round 6).
__global__ __launch_bounds__(256) void fill_conv_pack_kernel(const int* __restrict__ ei,
                                                             int* __restrict__ cursor,
                                                             unsigned short* __restrict__ adj,
                                                             const float* __restrict__ x,
                                                             unsigned short* __restrict__ xhi,
                                                             unsigned short* __restrict__ xlo,
                                                             const float* __restrict__ w,
                                                             const float* __restrict__ b,
                                                             unsigned short* __restrict__ wbt)
{
    const int bid = blockIdx.x;
    if (bid < CONV_BLOCKS) {
        // --- x -> (xhi, xlo): 8 elements/thread, fully coalesced ---
        const int t = bid * 256 + threadIdx.x;                   // < 160000 exact
        const float4 a = ((const float4*)x)[t * 2];
        const float4 c = ((const float4*)x)[t * 2 + 1];
        ushort4 h0, h1, l0, l1;
        h0.x = f2bf(a.x); l0.x = f2bf(a.x - bf2f(h0.x));
        h0.y = f2bf(a.y); l0.y = f2bf(a.y - bf2f(h0.y));
        h0.z = f2bf(a.z); l0.z = f2bf(a.z - bf2f(h0.z));
        h0.w = f2bf(a.w); l0.w = f2bf(a.w - bf2f(h0.w));
        h1.x = f2bf(c.x); l1.x = f2bf(c.x - bf2f(h1.x));
        h1.y = f2bf(c.y); l1.y = f2bf(c.y - bf2f(h1.y));
        h1.z = f2bf(c.z); l1.z = f2bf(c.z - bf2f(h1.z));
        h1.w = f2bf(c.w); l1.w = f2bf(c.w - bf2f(h1.w));
        ((ushort4*)xhi)[t * 2]     = h0;
        ((ushort4*)xhi)[t * 2 + 1] = h1;
        ((ushort4*)xlo)[t * 2]     = l0;
        ((ushort4*)xlo)[t * 2 + 1] = l1;
    } else if (bid < CONV_BLOCKS + FILL_BLOCKS) {
        // --- sliced bucket fill: 1 edge/thread, <=2 atomics, avg 0.25 ---
        const int fb    = bid - CONV_BLOCKS;
        const int slice = fb & (NSLICE - 1);
        const int chunk = fb >> 3;
        const int t = chunk * 256 + threadIdx.x;       // < 320000 exact
        const int2 p = ((const int2*)ei)[t];
        const int a = p.x, c = p.y;
        const bool aok = (unsigned)a < N_NODES && (unsigned)c < N_NODES;
        if (aok && (a & 7) == slice) {
            const int s0 = atomicAdd(&cursor[a * CSTR], 1);
            if (s0 < CAP) adj[(size_t)a * CAP + s0] = (unsigned short)c;
        }
        if (aok && (c & 7) == slice) {
            const int s1 = atomicAdd(&cursor[c * CSTR], 1);
            if (s1 < CAP) adj[(size_t)c * CAP + s1] = (unsigned short)a;
        }
    } else {
        // --- pack w,b into split-bf16 concat-K layout (16384 threads) ---
        const int t = (bid - CONV_BLOCKS - FILL_BLOCKS) * 256 + threadIdx.x;  // < 16384 exact
        const int n = t >> 7;          // output channel
        const int k = t & 127;         // input channel
        const float wv = w[n * CH + k];
        const float bv = b[n * CH + k];
        const unsigned short whi = f2bf(wv);
        const unsigned short wlo = f2bf(wv - bf2f(whi));
        const unsigned short bhi = f2bf(bv);
        const unsigned short blo = f2bf(bv - bf2f(bhi));
        unsigned short* row = wbt + (size_t)n * WBK;
        row[k]          = whi;
        row[CH + k]     = wlo;
        row[2 * CH + k] = bhi;
        row[3 * CH + k] = blo;
        row[4 * CH + k] = bhi;   // Bhi paired with Xlo segment
    }
}

// Kernel 2: FUSED gather-mean + MFMA GEMM + ReLU. 625 blocks x 512 threads
// (16 nodes/block = one 16-row m-tile). Exact round-7 structure; single
// change vs r7: gather loop unroll 4 -> 8 (8 independent index->row load
// chains in flight per lane; first unconfounded test of MLP depth --
// r8/r9's unroll-8 results were confounded with layout/shfl changes).
// Phase 1: 8 waves x 2 nodes, quarter-wave gather: lane = 16*h+l; quarter h
//   pulls neighbor 4*it+h; lane reads uint4 = 16 B = 8 bf16 ch. Agg row ->
//   LDS (AP-padded) -- no global aggb round-trip.
// Phase 2: wave wv owns output n-16th; K=640 concat MFMA loop (m89-verified
//   frag layouts, validated rounds 4-9); seg0/1 A-frags from LDS.
__global__ __launch_bounds__(512) void gather_mfma_kernel(const unsigned short* __restrict__ xhi,
                                                          const unsigned short* __restrict__ xlo,
                                                          const int* __restrict__ cursor,
                                                          const unsigned short* __restrict__ adj,
                                                          const unsigned short* __restrict__ wbt,
                                                          float* __restrict__ out)
{
    __shared__ unsigned short sh_a[NPB2 * AP];   // 4352 B, bf16 agg tile
    const int tid   = threadIdx.x;
    const int wv    = tid >> 6;                  // 0..7
    const int lane  = tid & 63;
    const int node0 = blockIdx.x * NPB2;         // grid = N_NODES/16 exactly

    // ---- Phase 1: gather + mean ----
    const int h = lane >> 4;                     // quarter 0..3 -> neighbor slot
    const int l = lane & 15;                     // 16 lanes x 8 ch = 128 ch

#pragma unroll
    for (int i = 0; i < 2; ++i) {
        const int nl   = wv * 2 + i;
        const int node = node0 + nl;
        const int deg  = cursor[node * CSTR];
        const int d    = deg < CAP ? deg : CAP;
        const unsigned short* nb = adj + (size_t)node * CAP;

        float4 accA = {0.f, 0.f, 0.f, 0.f};
        float4 accB = {0.f, 0.f, 0.f, 0.f};
        const int nit = (d + 3) >> 2;
#pragma unroll 8
        for (int it = 0; it < nit; ++it) {
            const int idx = 4 * it + h;            // max 127 < CAP
            int j = nb[idx];
            j = j < N_NODES ? j : 0;               // clamp stale garbage (re-poison)
            const uint4 q = ((const uint4*)(xhi + (size_t)j * CH))[l];
            const float m = idx < d ? 1.0f : 0.0f; // branch-free tail mask
            accA.x += m * __uint_as_float(q.x << 16);
            accA.y += m * __uint_as_float(q.x & 0xffff0000u);
            accA.z += m * __uint_as_float(q.y << 16);
            accA.w += m * __uint_as_float(q.y & 0xffff0000u);
            accB.x += m * __uint_as_float(q.z << 16);
            accB.y += m * __uint_as_float(q.z & 0xffff0000u);
            accB.z += m * __uint_as_float(q.w << 16);
            accB.w += m * __uint_as_float(q.w & 0xffff0000u);
        }
        // reduce across quarters (lanes l, l+16, l+32, l+48)
        accA.x += __shfl_xor(accA.x, 16, 64);
        accA.y += __shfl_xor(accA.y, 16, 64);
        accA.z += __shfl_xor(accA.z, 16, 64);
        accA.w += __shfl_xor(accA.w, 16, 64);
        accB.x += __shfl_xor(accB.x, 16, 64);
        accB.y += __shfl_xor(accB.y, 16, 64);
        accB.z += __shfl_xor(accB.z, 16, 64);
        accB.w += __shfl_xor(accB.w, 16, 64);
        accA.x += __shfl_xor(accA.x, 32, 64);
        accA.y += __shfl_xor(accA.y, 32, 64);
        accA.z += __shfl_xor(accA.z, 32, 64);
        accA.w += __shfl_xor(accA.w, 32, 64);
        accB.x += __shfl_xor(accB.x, 32, 64);
        accB.y += __shfl_xor(accB.y, 32, 64);
        accB.z += __shfl_xor(accB.z, 32, 64);
        accB.w += __shfl_xor(accB.w, 32, 64);

        if (h == 0) {
            const float inv = deg > 0 ? 1.0f / (float)deg : 0.0f;
            uint4 o;
            o.x = (unsigned)f2bf(accA.x * inv) | ((unsigned)f2bf(accA.y * inv) << 16);
            o.y = (unsigned)f2bf(accA.z * inv) | ((unsigned)f2bf(accA.w * inv) << 16);
            o.z = (unsigned)f2bf(accB.x * inv) | ((unsigned)f2bf(accB.y * inv) << 16);
            o.w = (unsigned)f2bf(accB.z * inv) | ((unsigned)f2bf(accB.w * inv) << 16);
            ((uint4*)(sh_a + (size_t)nl * AP))[l] = o;   // ch 8l..8l+7, 2-way alias
        }
    }
    __syncthreads();

    // ---- Phase 2: out = relu(Mcat @ wbt^T) for this block's 16 rows ----
    const int r  = lane & 15;
    const int q  = lane >> 4;
    const int n0 = wv * 16;                      // output-channel 16th
    const unsigned short* brow = wbt + (size_t)(n0 + r) * WBK;
    floatx4 acc = {0.f, 0.f, 0.f, 0.f};

#pragma unroll
    for (int seg = 0; seg < KSEG; ++seg) {
        const int wk = seg * CH;
#pragma unroll
        for (int ks = 0; ks < 4; ++ks) {
            const int k0 = ks * 32 + q * 8;
            short8v af;
            if (seg < 2) {
                af = *(const short8v*)(sh_a + (size_t)r * AP + k0);              // LDS
            } else if (seg < 4) {
                af = *(const short8v*)(xhi + (size_t)(node0 + r) * CH + k0);     // L2-hot
            } else {
                af = *(const short8v*)(xlo + (size_t)(node0 + r) * CH + k0);     // L2-hot
            }
            const short8v bf = *(const short8v*)(brow + wk + k0);
            acc = __builtin_amdgcn_mfma_f32_16x16x32_bf16(af, bf, acc, 0, 0, 0);
        }
    }

    const int mbase = node0 + q * 4;
#pragma unroll
    for (int rr = 0; rr < 4; ++rr) {
        float v = acc[rr];
        v = v > 0.f ? v : 0.f;
        out[(size_t)(mbase + rr) * CH + n0 + r] = v;
    }
}

// ---------------------------------------------------------------------------
extern "C" void kernel_launch(void* const* d_in, const int* in_sizes, int n_in,
                              void* d_out, int out_size, void* d_ws, size_t ws_size,
                              hipStream_t stream)
{
    const float* x  = (const float*)d_in[0];
    const int*   ei = (const int*)d_in[1];   // (E,2) int32
    const float* w  = (const float*)d_in[2];
    const float* b  = (const float*)d_in[3];
    float*       out = (float*)d_out;

    int*            cursor = (int*)d_ws;                                    // @ 0
    unsigned short* adj    = (unsigned short*)((char*)d_ws + 640000);       // 2.56 MB
    unsigned short* xhi    = (unsigned short*)((char*)d_ws + 3200000);      // 2.56 MB
    unsigned short* xlo    = (unsigned short*)((char*)d_ws + 5760000);      // 2.56 MB
    unsigned short* wbt    = (unsigned short*)((char*)d_ws + 8320000);      // 160 KB

    hipMemsetAsync(d_ws, 0, (size_t)N_NODES * CSTR * sizeof(int), stream);

    fill_conv_pack_kernel<<<CONV_BLOCKS + FILL_BLOCKS + PACK_BLOCKS, 256, 0, stream>>>(
        ei, cursor, adj, x, xhi, xlo, w, b, wbt);
    gather_mfma_kernel<<<N_NODES / NPB2, 512, 0, stream>>>(xhi, xlo, cursor, adj, wbt, out);
}